// Round 15
// baseline (6155.078 us; speedup 1.0000x reference)
//
#include <hip/hip_runtime.h>

typedef int i32x4 __attribute__((ext_vector_type(4)));
typedef float f32x4 __attribute__((ext_vector_type(4)));
typedef _Float16 h16x8 __attribute__((ext_vector_type(8)));

#define NB 64
#define NT 2048
#define ND 256
#define NH 256
#define NTHR 512
#define NCONS 4
#define GRID (NCONS + 192)
#define CHUNK 32
#define NCHUNK (NT / CHUNK)   // 64

// ---- consumer LDS byte map ----
#define WHT_OFF 0         // 64 KB: Wh B-frags, frag-linear: tile*1024 + lane*16
#define HA_OFF  65536     // 4 KB  int8 hA[16 row][256 k], k XOR-swz by row
#define VA_OFF  69632     // 4 KB  int8 vA[16 row][256 k], swz
#define LDS_BYTES 73728
// producer reuses first 16 KB as fp16 x[32 t][256 k], XOR-swizzled

#define AT_LD(p)    __hip_atomic_load((p), __ATOMIC_RELAXED, __HIP_MEMORY_SCOPE_AGENT)
#define AT_ST(p, v) __hip_atomic_store((p), (v), __ATOMIC_RELAXED, __HIP_MEMORY_SCOPE_AGENT)

__device__ __forceinline__ float sigmoid_f(float x) { return 1.f / (1.f + __expf(-x)); }
__device__ __forceinline__ float tanh_f(float x)    { return 1.f - 2.f / (1.f + __expf(2.f * x)); }
__device__ __forceinline__ float h16f(unsigned short u) {
    return (float)__builtin_bit_cast(_Float16, u);
}
__device__ __forceinline__ unsigned short f2h16(float f) {
    return __builtin_bit_cast(unsigned short, (_Float16)f);
}
__device__ __forceinline__ i32x4 mfma_i8(i32x4 a, i32x4 b, i32x4 c) {
    return __builtin_amdgcn_mfma_i32_16x16x64_i8(a, b, c, 0, 0, 0);
}
__device__ __forceinline__ f32x4 mfma_f16(h16x8 a, h16x8 b, f32x4 c) {
    return __builtin_amdgcn_mfma_f32_16x16x32_f16(a, b, c, 0, 0, 0);
}
__device__ __forceinline__ int q8(float v, float s) {
    int q = __float2int_rn(v * s);
    return q > 127 ? 127 : (q < -127 ? -127 : q);
}
// barrier draining only LDS (lgkm); global loads/stores stay in flight.
#define BAR_LDS() asm volatile("s_waitcnt lgkmcnt(0)\n\ts_barrier" ::: "memory")

// Grid 196 x 512, all co-resident.
//  bid < 4  : consumer — 16 batches via MFMA i8 16x16x64 (R13-validated frags).
//  bid >= 4 : producer (gate g, batch b) — x-projection via MFMA f16 16x16x32
//             (fp32 accum -> full precision), ring [slot][g][64b][128dw] fp16
//             col-pairs (dense, no write amplification).
extern "C" __global__ void __launch_bounds__(NTHR)
gru_fused(const float* __restrict__ x,
          const float* __restrict__ Wz, const float* __restrict__ bz,
          const float* __restrict__ Wr, const float* __restrict__ br,
          const float* __restrict__ Wh, const float* __restrict__ bh,
          float* __restrict__ out,
          unsigned* prodflag, unsigned* consflag,
          unsigned* pre, int ring)
{
    __shared__ __align__(16) unsigned smem_u[LDS_BYTES / 4];
    char* smem = (char*)smem_u;
    const int tid = threadIdx.x;
    const int bid = blockIdx.x;
    const int rmask = ring - 1;
    const size_t SLOTDW = 3 * 64 * 128;

    if (bid >= NCONS) {
        // ------- producer (gate g, batch b): MFMA f16 x-projection -------
        const int pg = bid - NCONS;     // 0..191
        const int g  = pg >> 6;         // 0=z 1=r 2=h
        const int b  = pg & 63;
        const float* W    = (g == 0) ? Wz : (g == 1) ? Wr : Wh;
        const float* bias = (g == 0) ? bz : (g == 1) ? br : bh;
        const int w  = tid >> 6;        // wave 0..7 -> cols w*32..+31
        const int l  = tid & 63;
        const int lr = l & 15;
        const int lg = l >> 4;

        // B-frags: Wx[k][col], lane col=lr, k = kt*32 + lg*8 + j  (64 VGPRs)
        h16x8 bf[8][2];
        #pragma unroll
        for (int kt = 0; kt < 8; ++kt)
            #pragma unroll
            for (int nt = 0; nt < 2; ++nt) {
                const int col = w * 32 + nt * 16 + lr;
                h16x8 v;
                #pragma unroll
                for (int j = 0; j < 8; ++j)
                    v[j] = (_Float16)W[(kt * 32 + lg * 8 + j) * NH + col];
                bf[kt][nt] = v;
            }
        const float bv0 = bias[w * 32 + lr];
        const float bv1 = bias[w * 32 + 16 + lr];

        for (int ch = 0; ch < NCHUNK; ++ch) {
            const int lead = ch * CHUNK + CHUNK - ring;
            if (lead > 0) {
                if (tid == 0) {
                    unsigned it = 0;
                    while ((int)AT_LD(&consflag[b >> 4]) < lead) {
                        __builtin_amdgcn_s_sleep(8);
                        if (++it > (1u << 20)) break;
                    }
                }
                __syncthreads();
            }
            const int t0 = ch * CHUNK;
            {   // stage x chunk -> fp16 LDS [32 row][256 k], 16B-granule XOR swz
                const float4* xs = reinterpret_cast<const float4*>(
                    x + ((size_t)b * NT + t0) * ND);
                #pragma unroll
                for (int rep = 0; rep < 4; ++rep) {
                    const int f   = rep * NTHR + tid;   // 0..2047 float4s
                    const float4 v = xs[f];
                    const int row = f >> 6;
                    const int k8  = (f & 63) * 8;       // byte offset of 4 halfs
                    unsigned lo = (unsigned)f2h16(v.x) | ((unsigned)f2h16(v.y) << 16);
                    unsigned hi = (unsigned)f2h16(v.z) | ((unsigned)f2h16(v.w) << 16);
                    uint2 pk; pk.x = lo; pk.y = hi;
                    *reinterpret_cast<uint2*>(smem + row * 512 +
                        (k8 ^ ((row & 7) << 4))) = pk;
                }
            }
            __syncthreads();
            // GEMM: [32 t x 256 k] x [256 k x 32 cols(this wave)]
            f32x4 acc[2][2] = {{{0,0,0,0},{0,0,0,0}},{{0,0,0,0},{0,0,0,0}}};
            #pragma unroll
            for (int kt = 0; kt < 8; ++kt) {
                #pragma unroll
                for (int mt = 0; mt < 2; ++mt) {
                    const int row = mt * 16 + lr;
                    const h16x8 a = *reinterpret_cast<const h16x8*>(
                        smem + row * 512 + ((kt * 64 + lg * 16) ^ ((row & 7) << 4)));
                    acc[mt][0] = mfma_f16(a, bf[kt][0], acc[mt][0]);
                    acc[mt][1] = mfma_f16(a, bf[kt][1], acc[mt][1]);
                }
            }
            // epilogue: +bias, fp16 col-pair pack, dense ring stores
            #pragma unroll
            for (int mt = 0; mt < 2; ++mt) {
                #pragma unroll
                for (int i = 0; i < 4; ++i) {
                    const int trow = mt * 16 + lg * 4 + i;
                    const size_t sb = (size_t)((t0 + trow) & rmask) * SLOTDW
                                    + (size_t)(g * 64 + b) * 128;
                    const float v0 = acc[mt][0][i] + bv0;
                    const float v1 = acc[mt][1][i] + bv1;
                    const int h0 = (int)f2h16(v0);
                    const int h1 = (int)f2h16(v1);
                    const int p0 = __shfl_xor(h0, 1, 64);
                    const int p1 = __shfl_xor(h1, 1, 64);
                    if (!(lr & 1)) {
                        const int c0 = w * 32 + lr;        // even col
                        const int c1 = w * 32 + 16 + lr;
                        AT_ST(pre + sb + (c0 >> 1),
                              (unsigned)h0 | ((unsigned)p0 << 16));
                        AT_ST(pre + sb + (c1 >> 1),
                              (unsigned)h1 | ((unsigned)p1 << 16));
                    }
                }
            }
            asm volatile("s_waitcnt vmcnt(0)" ::: "memory");
            __syncthreads();
            if (tid == 0) AT_ST(&prodflag[g * 64 + b], (unsigned)(ch + 1));
            __syncthreads();
        }
        return;
    }

    // ---------------- consumer: 16 batches via MFMA (R13-validated) ----------
    const int bg = bid;              // group 0..3 -> batches bg*16..+15
    const int B0 = bg * 16;
    const int w  = tid >> 6;         // wave -> cols w*32..+31
    const int l  = tid & 63;
    const int lr = l & 15;           // A row / B,C col in tile
    const int lg = l >> 4;           // k-group / C row-group
    const int r0 = lg * 4;
    const int colN[2] = { w * 32 + lr, w * 32 + 16 + lr };
    const int cd[2]   = { colN[0] >> 1, colN[1] >> 1 };
    const int psh     = (lr & 1) * 16;   // fp16 half-select in packed dword

    // per-col scales for the 3 h-part gates
    float mxz[2] = {1e-8f, 1e-8f}, mxr[2] = {1e-8f, 1e-8f}, mxh[2] = {1e-8f, 1e-8f};
    for (int k = 0; k < 256; ++k) {
        #pragma unroll
        for (int nt = 0; nt < 2; ++nt) {
            mxz[nt] = fmaxf(mxz[nt], fabsf(Wz[(ND + k) * NH + colN[nt]]));
            mxr[nt] = fmaxf(mxr[nt], fabsf(Wr[(ND + k) * NH + colN[nt]]));
            mxh[nt] = fmaxf(mxh[nt], fabsf(Wh[(ND + k) * NH + colN[nt]]));
        }
    }
    float dqz[2], dqr[2], dqh[2];
    #pragma unroll
    for (int nt = 0; nt < 2; ++nt) {
        dqz[nt] = mxz[nt] / 16129.f;
        dqr[nt] = mxr[nt] / 16129.f;
        dqh[nt] = mxh[nt] / 16129.f;
    }
    // z,r B-frags in regs: B[k][col], lane col=lr, k=kt*64+lg*16+j
    i32x4 bzf[4], brf[4], bzf1[4], brf1[4];
    #pragma unroll
    for (int nt = 0; nt < 2; ++nt) {
        const int col = colN[nt];
        const float qz = 127.f / mxz[nt], qr = 127.f / mxr[nt];
        #pragma unroll
        for (int kt = 0; kt < 4; ++kt) {
            int dz[4], dr[4];
            #pragma unroll
            for (int d = 0; d < 4; ++d) {
                unsigned az = 0, ar = 0;
                #pragma unroll
                for (int bb = 0; bb < 4; ++bb) {
                    const int k = kt * 64 + lg * 16 + d * 4 + bb;
                    az |= ((unsigned)(q8(Wz[(ND + k) * NH + col], qz) & 255)) << (8 * bb);
                    ar |= ((unsigned)(q8(Wr[(ND + k) * NH + col], qr) & 255)) << (8 * bb);
                }
                dz[d] = (int)az; dr[d] = (int)ar;
            }
            if (nt == 0) { bzf[kt]  = (i32x4){dz[0],dz[1],dz[2],dz[3]};
                           brf[kt]  = (i32x4){dr[0],dr[1],dr[2],dr[3]}; }
            else         { bzf1[kt] = (i32x4){dz[0],dz[1],dz[2],dz[3]};
                           brf1[kt] = (i32x4){dr[0],dr[1],dr[2],dr[3]}; }
        }
    }
    // Wh B-frags -> LDS, frag-linear (tile*1024 + lane*16): conflict-free
    #pragma unroll
    for (int nt = 0; nt < 2; ++nt) {
        const int col = colN[nt];
        const float qh = 127.f / mxh[nt];
        #pragma unroll
        for (int kt = 0; kt < 4; ++kt) {
            int dh[4];
            #pragma unroll
            for (int d = 0; d < 4; ++d) {
                unsigned ah = 0;
                #pragma unroll
                for (int bb = 0; bb < 4; ++bb) {
                    const int k = kt * 64 + lg * 16 + d * 4 + bb;
                    ah |= ((unsigned)(q8(Wh[(ND + k) * NH + col], qh) & 255)) << (8 * bb);
                }
                dh[d] = (int)ah;
            }
            *(i32x4*)(smem + WHT_OFF + ((((w * 2 + nt) * 4 + kt) * 64 + l) << 4)) =
                (i32x4){dh[0], dh[1], dh[2], dh[3]};
        }
    }
    // zero hA + vA (8 KB); h_prev in regs (lane owns its C-tile elems)
    for (int i = tid; i < 2048; i += NTHR) smem_u[HA_OFF / 4 + i] = 0u;
    float hp0[4] = {0.f, 0.f, 0.f, 0.f};
    float hp1[4] = {0.f, 0.f, 0.f, 0.f};

    // wait for chunk 0 of the 48 feeding (gate, batch) producers
    if (tid < 48) {
        const int fl = (tid >> 4) * 64 + B0 + (tid & 15);
        unsigned it = 0;
        while (AT_LD(&prodflag[fl]) < 1u) {
            __builtin_amdgcn_s_sleep(8);
            if (++it > (1u << 20)) break;
        }
    }
    __syncthreads();

    #pragma unroll 1
    for (int t = 0; t < NT; ++t) {
        if (t && !(t & (CHUNK - 1))) {     // chunk boundary
            if (tid == 0) AT_ST(&consflag[bg], (unsigned)t);
            const unsigned need = (unsigned)((t >> 5) + 1);
            if (tid < 48) {
                const int fl = (tid >> 4) * 64 + B0 + (tid & 15);
                unsigned it = 0;
                while (AT_LD(&prodflag[fl]) < need) {
                    __builtin_amdgcn_s_sleep(8);
                    if (++it > (1u << 20)) break;
                }
            }
            __syncthreads();
        }
        const size_t sb = (size_t)(t & rmask) * SLOTDW;
        // z,r pre-activations (fp16 col-pairs, issued early)
        unsigned pzd[2][4], prd[2][4];
        #pragma unroll
        for (int i = 0; i < 4; ++i) {
            const size_t rz = sb + (size_t)(0 * 64 + B0 + r0 + i) * 128;
            const size_t rr = sb + (size_t)(1 * 64 + B0 + r0 + i) * 128;
            pzd[0][i] = AT_LD(pre + rz + cd[0]);
            pzd[1][i] = AT_LD(pre + rz + cd[1]);
            prd[0][i] = AT_LD(pre + rr + cd[0]);
            prd[1][i] = AT_LD(pre + rr + cd[1]);
        }

        // ---- stage A: z,r GEMMs over hA ----
        i32x4 zc0 = {0,0,0,0}, zc1 = {0,0,0,0}, rc0 = {0,0,0,0}, rc1 = {0,0,0,0};
        #pragma unroll
        for (int kt = 0; kt < 4; ++kt) {
            const i32x4 ha = *(const i32x4*)(smem + HA_OFF + lr * 256 +
                               ((kt * 64 + lg * 16) ^ ((lr & 7) << 4)));
            zc0 = mfma_i8(ha, bzf[kt],  zc0);
            zc1 = mfma_i8(ha, bzf1[kt], zc1);
            rc0 = mfma_i8(ha, brf[kt],  rc0);
            rc1 = mfma_i8(ha, brf1[kt], rc1);
        }
        // epilogue A: gates, v = r*h_prev -> int8 vA
        float zz0[4], zz1[4];
        #pragma unroll
        for (int i = 0; i < 4; ++i) {
            const int row = r0 + i;
            const float z0 = sigmoid_f((float)zc0[i] * dqz[0]
                             + h16f((unsigned short)(pzd[0][i] >> psh)));
            const float rg0 = sigmoid_f((float)rc0[i] * dqr[0]
                             + h16f((unsigned short)(prd[0][i] >> psh)));
            const float z1 = sigmoid_f((float)zc1[i] * dqz[1]
                             + h16f((unsigned short)(pzd[1][i] >> psh)));
            const float rg1 = sigmoid_f((float)rc1[i] * dqr[1]
                             + h16f((unsigned short)(prd[1][i] >> psh)));
            smem[VA_OFF + row * 256 + (colN[0] ^ ((row & 7) << 4))] =
                (char)__float2int_rn(rg0 * hp0[i] * 127.f);
            smem[VA_OFF + row * 256 + (colN[1] ^ ((row & 7) << 4))] =
                (char)__float2int_rn(rg1 * hp1[i] * 127.f);
            zz0[i] = z0; zz1[i] = z1;
        }
        BAR_LDS();   // vA complete

        // h-gate pre-activations (hidden under stage B MFMAs)
        unsigned phd[2][4];
        #pragma unroll
        for (int i = 0; i < 4; ++i) {
            const size_t rh = sb + (size_t)(2 * 64 + B0 + r0 + i) * 128;
            phd[0][i] = AT_LD(pre + rh + cd[0]);
            phd[1][i] = AT_LD(pre + rh + cd[1]);
        }
        // ---- stage B: h_hat GEMM over vA ----
        i32x4 hc0 = {0,0,0,0}, hc1 = {0,0,0,0};
        #pragma unroll
        for (int kt = 0; kt < 4; ++kt) {
            const i32x4 va = *(const i32x4*)(smem + VA_OFF + lr * 256 +
                               ((kt * 64 + lg * 16) ^ ((lr & 7) << 4)));
            const i32x4 wh0 = *(const i32x4*)(smem + WHT_OFF +
                               ((((w * 2 + 0) * 4 + kt) * 64 + l) << 4));
            const i32x4 wh1 = *(const i32x4*)(smem + WHT_OFF +
                               ((((w * 2 + 1) * 4 + kt) * 64 + l) << 4));
            hc0 = mfma_i8(va, wh0, hc0);
            hc1 = mfma_i8(va, wh1, hc1);
        }
        // epilogue B: tanh, blend, store, update state
        #pragma unroll
        for (int i = 0; i < 4; ++i) {
            const int row = r0 + i;
            const float hh0 = tanh_f((float)hc0[i] * dqh[0]
                              + h16f((unsigned short)(phd[0][i] >> psh)));
            const float hh1 = tanh_f((float)hc1[i] * dqh[1]
                              + h16f((unsigned short)(phd[1][i] >> psh)));
            const float hn0 = hp0[i] + zz0[i] * (hh0 - hp0[i]);
            const float hn1 = hp1[i] + zz1[i] * (hh1 - hp1[i]);
            hp0[i] = hn0; hp1[i] = hn1;
            out[((size_t)(B0 + row) * NT + t) * NH + colN[0]] = hn0;
            out[((size_t)(B0 + row) * NT + t) * NH + colN[1]] = hn1;
            smem[HA_OFF + row * 256 + (colN[0] ^ ((row & 7) << 4))] =
                (char)__float2int_rn(hn0 * 127.f);
            smem[HA_OFF + row * 256 + (colN[1] ^ ((row & 7) << 4))] =
                (char)__float2int_rn(hn1 * 127.f);
        }
        BAR_LDS();   // hA = h_t everywhere
    }
}

extern "C" void kernel_launch(void* const* d_in, const int* in_sizes, int n_in,
                              void* d_out, int out_size, void* d_ws, size_t ws_size,
                              hipStream_t stream) {
    const float* x  = (const float*)d_in[0];
    const float* Wz = (const float*)d_in[1];
    const float* bz = (const float*)d_in[2];
    const float* Wr = (const float*)d_in[3];
    const float* br = (const float*)d_in[4];
    const float* Wh = (const float*)d_in[5];
    const float* bh = (const float*)d_in[6];
    float* outp = (float*)d_out;

    // ring: per-slot bytes = 3*64*128*4 = 98304
    const size_t base = 4096;
    int ring = 32;
    for (int r = 2048; r >= 32; r >>= 1) {
        const size_t need = base + (size_t)r * 98304;
        if (need <= ws_size) { ring = r; break; }
    }
    char* w = (char*)d_ws;
    unsigned* prodflag = (unsigned*)w;              // [3][64]
    unsigned* consflag = (unsigned*)(w + 1024);     // [4]
    unsigned* pre = (unsigned*)(w + base);          // [ring][3][64][128] dw

    hipMemsetAsync(w, 0, 4096, stream);  // flags must start at 0 each launch
    gru_fused<<<GRID, NTHR, 0, stream>>>(x, Wz, bz, Wr, br, Wh, bh, outp,
                                         prodflag, consflag, pre, ring);
}